// Round 4
// baseline (175.805 us; speedup 1.0000x reference)
//
#include <hip/hip_runtime.h>
#include <hip/hip_bf16.h>
#include <cstdint>

#define N 4096
#define L2E 1.44269504088896f

typedef __attribute__((ext_vector_type(8))) short bf16x8;
typedef __attribute__((ext_vector_type(4))) float f32x4;
typedef __attribute__((ext_vector_type(16))) float f32x16;

__device__ __forceinline__ float elu_f(float x){ return x > 0.f ? x : __expf(x) - 1.f; }
__device__ __forceinline__ short bfc(float x){
  __hip_bfloat16 h = __float2bfloat16(x);
  return *reinterpret_cast<short*>(&h);
}

// ---------------- adj -> transposed bitmask: bitsT[word][n] ----------------
__global__ __launch_bounds__(256) void mask_kernel(const int* __restrict__ adj,
                                                   unsigned long long* __restrict__ bitsT){
  int gwave = (blockIdx.x * blockDim.x + threadIdx.x) >> 6;
  int lane = threadIdx.x & 63;
  if (gwave >= N) return;
  const int* arow = adj + (size_t)gwave * N;
  for (int w = 0; w < 64; ++w){
    unsigned long long b = __ballot(arow[(w << 6) + lane] != 0);
    if (lane == 0) bitsT[(size_t)w * N + gwave] = b;
  }
}

// ---------------- layer 1: Wh1[h][n][o] = x(128) . W_heads[h](128x64) ------
__global__ __launch_bounds__(256) void wh1_kernel(const float* __restrict__ x,
                                                  const float* __restrict__ W,
                                                  float* __restrict__ Wh){
  int n0 = blockIdx.x * 16;
  int tid = threadIdx.x;
  int h = tid >> 5;
  int o = (tid & 31) * 2;
  const float* Wp = W + h * 8192 + o;
  float acc0[16], acc1[16];
  #pragma unroll
  for (int r = 0; r < 16; ++r){ acc0[r] = 0.f; acc1[r] = 0.f; }
  for (int f4 = 0; f4 < 32; ++f4){
    float2 wv0 = *(const float2*)(Wp + (f4*4+0)*64);
    float2 wv1 = *(const float2*)(Wp + (f4*4+1)*64);
    float2 wv2 = *(const float2*)(Wp + (f4*4+2)*64);
    float2 wv3 = *(const float2*)(Wp + (f4*4+3)*64);
    #pragma unroll
    for (int r = 0; r < 16; ++r){
      float4 xv = *(const float4*)(x + (size_t)(n0 + r)*128 + f4*4);
      acc0[r] += xv.x*wv0.x; acc1[r] += xv.x*wv0.y;
      acc0[r] += xv.y*wv1.x; acc1[r] += xv.y*wv1.y;
      acc0[r] += xv.z*wv2.x; acc1[r] += xv.z*wv2.y;
      acc0[r] += xv.w*wv3.x; acc1[r] += xv.w*wv3.y;
    }
  }
  #pragma unroll
  for (int r = 0; r < 16; ++r){
    float2 st; st.x = acc0[r]; st.y = acc1[r];
    *(float2*)(Wh + ((size_t)(h*N) + n0 + r)*64 + o) = st;
  }
}

// ---------------- layer 2: Wh2[n][o] = hmat(512) . W_out(512x64) -----------
__global__ __launch_bounds__(256) void wh2_kernel(const float* __restrict__ hmat,
                                                  const float* __restrict__ W,
                                                  float* __restrict__ Wh2){
  int n0 = blockIdx.x * 16;
  int tid = threadIdx.x;
  int o = tid & 63;
  int rq = tid >> 6;
  float acc[4] = {0.f,0.f,0.f,0.f};
  for (int f4 = 0; f4 < 128; ++f4){
    float w0 = W[(f4*4+0)*64 + o];
    float w1 = W[(f4*4+1)*64 + o];
    float w2 = W[(f4*4+2)*64 + o];
    float w3 = W[(f4*4+3)*64 + o];
    #pragma unroll
    for (int r = 0; r < 4; ++r){
      float4 xv = *(const float4*)(hmat + (size_t)(n0 + rq*4 + r)*512 + f4*4);
      acc[r] += xv.x*w0 + xv.y*w1 + xv.z*w2 + xv.w*w3;
    }
  }
  #pragma unroll
  for (int r = 0; r < 4; ++r)
    Wh2[(size_t)(n0 + rq*4 + r)*64 + o] = acc[r];
}

// ---------------- f1/f2 per (h,n), pre-scaled by log2(e) -------------------
__global__ __launch_bounds__(256) void fvec_kernel(const float* __restrict__ Wh,
                                                   const float* __restrict__ a,
                                                   float* __restrict__ f1v, float* __restrict__ f2v,
                                                   int Hn){
  int gw = (blockIdx.x * 256 + threadIdx.x) >> 6;
  int lane = threadIdx.x & 63;
  if (gw >= Hn * N) return;
  int h = gw >> 12;
  float v = Wh[(size_t)gw * 64 + lane];
  float a1 = a[h*128 + lane];
  float a2 = a[h*128 + 64 + lane];
  float p1 = v * a1, p2 = v * a2;
  #pragma unroll
  for (int s = 32; s; s >>= 1){ p1 += __shfl_xor(p1, s); p2 += __shfl_xor(p2, s); }
  if (lane == 0){
    f1v[gw] = p1 * L2E;
    f2v[gw] = p2 * L2E;
  }
}

// ---------------- transpose + bf16: WhT[h][o][n] = bf16(Wh[h][n][o]) -------
__global__ __launch_bounds__(256) void trans_kernel(const float* __restrict__ Wh,
                                                    ushort* __restrict__ WhT){
  __shared__ float T[64][65];
  int h = blockIdx.x >> 6;
  int n0 = (blockIdx.x & 63) * 64;
  const float* src = Wh + ((size_t)h*N + n0)*64;
  #pragma unroll
  for (int i = 0; i < 16; ++i){
    int idx = threadIdx.x + i*256;
    T[idx >> 6][idx & 63] = src[idx];
  }
  __syncthreads();
  int o = threadIdx.x >> 2;
  int nq = (threadIdx.x & 3) * 16;
  ushort tmp[16];
  #pragma unroll
  for (int j = 0; j < 16; ++j) tmp[j] = (ushort)bfc(T[nq + j][o]);
  ushort* dst = WhT + ((size_t)(h*64 + o))*N + n0 + nq;
  *(int4*)dst = *(int4*)&tmp[0];
  *(int4*)(dst + 8) = *(int4*)&tmp[8];
}

// ---------------- MFMA masked-softmax aggregation (32x32x16) ---------------
// block = 256 thr (4 waves); output 128 n x 64 o per (h, tile, chunk).
// wave w owns rows n0+w*32 .. +31 (32x32 frags, 2 col-blocks + den ones-col).
__global__ __launch_bounds__(256, 4) void attn32_kernel(
    const ushort* __restrict__ WhT, const unsigned long long* __restrict__ bitsT,
    const float* __restrict__ f1v, const float* __restrict__ f2v,
    float* __restrict__ num, float* __restrict__ den, int Hn, int nchunks)
{
  __shared__ ushort Bt[4096];      // [64 o][64 m] bf16, XOR-swizzled 16B chunks
  const int bid  = blockIdx.x;
  const int t    = bid & 31;
  const int rest = bid >> 5;
  const int h    = rest % Hn;
  const int c    = rest / Hn;
  const int n0   = t << 7;               // 128 rows per block
  const int mlen = N / nchunks;
  const int m0b  = c * mlen;
  const int tid  = threadIdx.x;
  const int w    = tid >> 6;
  const int l    = tid & 63;
  const int r32  = l & 31;
  const int kg2  = l >> 5;
  const int n    = n0 + w*32 + r32;      // this lane's output row

  const float f1r = f1v[h*N + n];
  const float* f2H = f2v + (size_t)h * N;
  const ushort* Wb = WhT + (size_t)h * 64 * N;

  // staging decomposition: thread tid stages rows so and so+32, one swizzled
  // 16B chunk each. slot s of row o holds source chunk s^(o&7).
  const int so   = tid >> 3;             // 0..31
  const int slot = tid & 7;
  const int sc   = slot ^ (so & 7);      // source m-chunk for this slot

  // den B-fragment: column 0 = 1.0, in registers (no LDS)
  bf16x8 BD;
  #pragma unroll
  for (int j = 0; j < 8; ++j) BD[j] = (r32 == 0) ? (short)0x3F80 : (short)0;

  f32x16 acc0 = {}, acc1 = {}, accD = {};

  #pragma unroll 1
  for (int mt = 0; mt < mlen; mt += 64){
    const int m0 = m0b + mt;
    __syncthreads();                     // previous tile's B reads complete
    // ---- stage B tile: both 32-row halves ----
    int4 sv0 = *(const int4*)(Wb + (size_t)so*N      + m0 + sc*8);
    int4 sv1 = *(const int4*)(Wb + (size_t)(so+32)*N + m0 + sc*8);
    // ---- build A fragments in registers (32 weights per lane) ----
    unsigned long long adjw = bitsT[(size_t)(m0 >> 6)*N + n];
    bf16x8 Afr[4];
    #pragma unroll
    for (int ks = 0; ks < 4; ++ks){
      const float* fp = f2H + m0 + ks*16 + kg2*8;
      f32x4 fA = *(const f32x4*)fp;
      f32x4 fB = *(const f32x4*)(fp + 4);
      uint32_t bb = (uint32_t)(adjw >> (ks*16 + kg2*8)) & 0xFFu;
      bf16x8 A;
      #pragma unroll
      for (int j = 0; j < 4; ++j){
        float s0 = f1r + fA[j];
        float s1 = f1r + fB[j];
        float e0 = __builtin_amdgcn_exp2f(fmaxf(s0, 0.2f*s0));
        float e1 = __builtin_amdgcn_exp2f(fmaxf(s1, 0.2f*s1));
        e0 = ((bb >> j) & 1u)     ? e0 : 0.f;
        e1 = ((bb >> (4+j)) & 1u) ? e1 : 0.f;
        A[j]   = bfc(e0);
        A[4+j] = bfc(e1);
      }
      Afr[ks] = A;
    }
    *(int4*)&Bt[(size_t)so*64      + slot*8] = sv0;   // linear LDS store
    *(int4*)&Bt[(size_t)(so+32)*64 + slot*8] = sv1;   // (swizzle in source)
    __syncthreads();                     // B tile visible
    // ---- MFMA: 4 k-steps x (2 col-blocks + den) ----
    #pragma unroll
    for (int ks = 0; ks < 4; ++ks){
      const int ci = ks*2 + kg2;
      const int sw = (ci ^ (r32 & 7)) << 3;
      bf16x8 B0 = *(const bf16x8*)&Bt[ r32      *64 + sw];
      bf16x8 B1 = *(const bf16x8*)&Bt[(32 + r32)*64 + sw];
      acc0 = __builtin_amdgcn_mfma_f32_32x32x16_bf16(Afr[ks], B0, acc0, 0, 0, 0);
      acc1 = __builtin_amdgcn_mfma_f32_32x32x16_bf16(Afr[ks], B1, acc1, 0, 0, 0);
      accD = __builtin_amdgcn_mfma_f32_32x32x16_bf16(Afr[ks], BD, accD, 0, 0, 0);
    }
  }

  // ---- write num (C/D map: col = l&31, row = (r&3)+8*(r>>2)+4*kg2) ----
  float* nb = num + ((size_t)(c*Hn + h)*N + n0 + w*32)*64;
  #pragma unroll
  for (int r = 0; r < 16; ++r){
    int row = (r & 3) + 8*(r >> 2) + 4*kg2;
    nb[(size_t)row*64 +      r32] = acc0[r];
    nb[(size_t)row*64 + 32 + r32] = acc1[r];
  }
  // ---- write den (column 0 of accD lives in lanes with r32==0) ----
  if (r32 == 0){
    float* db = den + (size_t)(c*Hn + h)*N + n0 + w*32;
    #pragma unroll
    for (int r = 0; r < 16; ++r){
      int row = (r & 3) + 8*(r >> 2) + 4*kg2;
      db[row] = accD[r];
    }
  }
}

// ---------------- finalize layer 1: hmat = elu(sum num / sum den) ----------
__global__ __launch_bounds__(256) void fin1_kernel(const float* __restrict__ num,
                                                   const float* __restrict__ den,
                                                   float* __restrict__ hmat, int nch){
  int idx = blockIdx.x * 256 + threadIdx.x;     // over 8*N*64
  int o = idx & 63;
  int hn = idx >> 6;
  int n = hn & (N - 1);
  int h = hn >> 12;
  float nu = 0.f, de = 0.f;
  for (int cc = 0; cc < nch; ++cc){
    nu += num[(size_t)idx + (size_t)cc*(8*N*64)];
    de += den[hn + cc*(8*N)];
  }
  hmat[(size_t)n*512 + h*64 + o] = elu_f(nu / de);
}

// ---------------- finalize layer 2: out = elu(sum num / sum den) -----------
__global__ __launch_bounds__(256) void fin2_kernel(const float* __restrict__ num,
                                                   const float* __restrict__ den,
                                                   float* __restrict__ out, int nch){
  int idx = blockIdx.x * 256 + threadIdx.x;     // over N*64
  int n = idx >> 6;
  float s = 0.f, d = 0.f;
  for (int cc = 0; cc < nch; ++cc){
    s += num[(size_t)idx + (size_t)cc*(N*64)];
    d += den[n + cc*N];
  }
  out[idx] = elu_f(s / d);
}

extern "C" void kernel_launch(void* const* d_in, const int* in_sizes, int n_in,
                              void* d_out, int out_size, void* d_ws, size_t ws_size,
                              hipStream_t stream){
  const float* x       = (const float*)d_in[0];
  const int*   adj     = (const int*)d_in[1];
  const float* W_heads = (const float*)d_in[3];
  const float* a_heads = (const float*)d_in[4];
  const float* W_out   = (const float*)d_in[5];
  const float* a_out   = (const float*)d_in[6];
  float* out = (float*)d_out;
  char* ws = (char*)d_ws;

  const size_t MB = 1u << 20;
  unsigned long long* bitsT = (unsigned long long*)(ws);
  float*  Wh1f = (float*)(ws + 2*MB);
  ushort* Wh1T = (ushort*)(ws + 10*MB);
  float*  f1v1 = (float*)(ws + 14*MB);
  float*  f2v1 = (float*)(ws + 14*MB + 128*1024);
  float*  den1 = (float*)(ws + 14*MB + 512*1024);
  float*  num1 = (float*)(ws + 15*MB);
  float*  hmat = Wh1f;
  float*  Wh2f = (float*)(ws + 10*MB);            // 1 MB
  ushort* Wh2T = (ushort*)(ws + 11*MB);           // 0.5 MB
  float*  f1v2 = (float*)(ws + 12*MB);            // 16 KB
  float*  f2v2 = (float*)(ws + 12*MB + 64*1024);  // 16 KB
  float*  den2 = (float*)(ws + 13*MB);            // 256 KB
  float*  num2 = num1;                            // 16 chunks x 1 MB

  const int nch1 = (ws_size >= (size_t)48*MB) ? 4 : 2;
  const int nch2 = 16;

  mask_kernel<<<1024, 256, 0, stream>>>(adj, bitsT);
  wh1_kernel<<<256, 256, 0, stream>>>(x, W_heads, Wh1f);
  fvec_kernel<<<8192, 256, 0, stream>>>(Wh1f, a_heads, f1v1, f2v1, 8);
  trans_kernel<<<512, 256, 0, stream>>>(Wh1f, Wh1T);
  attn32_kernel<<<32*8*nch1, 256, 0, stream>>>(Wh1T, bitsT, f1v1, f2v1, num1, den1, 8, nch1);
  fin1_kernel<<<8192, 256, 0, stream>>>(num1, den1, hmat, nch1);
  wh2_kernel<<<256, 256, 0, stream>>>(hmat, W_out, Wh2f);
  fvec_kernel<<<1024, 256, 0, stream>>>(Wh2f, a_out, f1v2, f2v2, 1);
  trans_kernel<<<64, 256, 0, stream>>>(Wh2f, Wh2T);
  attn32_kernel<<<32*1*nch2, 256, 0, stream>>>(Wh2T, bitsT, f1v2, f2v2, num2, den2, 1, nch2);
  fin2_kernel<<<1024, 256, 0, stream>>>(num2, den2, out, nch2);
}

// Round 6
// 154.877 us; speedup vs baseline: 1.1351x; 1.1351x over previous
//
#include <hip/hip_runtime.h>
#include <hip/hip_bf16.h>
#include <cstdint>

#define N 4096
#define L2E 1.44269504088896f

typedef __attribute__((ext_vector_type(8))) short bf16x8;
typedef __attribute__((ext_vector_type(4))) float f32x4;
typedef __attribute__((ext_vector_type(16))) float f32x16;

__device__ __forceinline__ float elu_f(float x){ return x > 0.f ? x : __expf(x) - 1.f; }
__device__ __forceinline__ short bfc(float x){
  __hip_bfloat16 h = __float2bfloat16(x);
  return *reinterpret_cast<short*>(&h);
}

// ---------------- adj -> transposed bitmask: bitsT[word][n] ----------------
__global__ __launch_bounds__(256) void mask_kernel(const int* __restrict__ adj,
                                                   unsigned long long* __restrict__ bitsT){
  int gwave = (blockIdx.x * blockDim.x + threadIdx.x) >> 6;
  int lane = threadIdx.x & 63;
  if (gwave >= N) return;
  const int* arow = adj + (size_t)gwave * N;
  #pragma unroll 8
  for (int w = 0; w < 64; ++w){
    unsigned long long b = __ballot(arow[(w << 6) + lane] != 0);
    if (lane == 0) bitsT[(size_t)w * N + gwave] = b;
  }
}

// ------- fused layer-1 projection: Wh (bf16, transposed) + e-vectors -------
// block = 16 rows x all 8 heads. thread: h = tid>>5, o-pair = 2*(tid&31).
__global__ __launch_bounds__(256) void wh1f_kernel(
    const float* __restrict__ x, const float* __restrict__ W, const float* __restrict__ a,
    ushort* __restrict__ WhT, float* __restrict__ e1p, float* __restrict__ e1n,
    float* __restrict__ Tv, float* __restrict__ e2p, float* __restrict__ e2n){
  int n0 = blockIdx.x * 16;
  int tid = threadIdx.x;
  int h = tid >> 5;
  int g = tid & 31;
  int o = g * 2;
  const float* Wp = W + h * 8192 + o;
  float acc0[16], acc1[16];
  #pragma unroll
  for (int r = 0; r < 16; ++r){ acc0[r] = 0.f; acc1[r] = 0.f; }
  for (int f4 = 0; f4 < 32; ++f4){
    float2 wv0 = *(const float2*)(Wp + (f4*4+0)*64);
    float2 wv1 = *(const float2*)(Wp + (f4*4+1)*64);
    float2 wv2 = *(const float2*)(Wp + (f4*4+2)*64);
    float2 wv3 = *(const float2*)(Wp + (f4*4+3)*64);
    #pragma unroll
    for (int r = 0; r < 16; ++r){
      float4 xv = *(const float4*)(x + (size_t)(n0 + r)*128 + f4*4);
      acc0[r] += xv.x*wv0.x; acc1[r] += xv.x*wv0.y;
      acc0[r] += xv.y*wv1.x; acc1[r] += xv.y*wv1.y;
      acc0[r] += xv.z*wv2.x; acc1[r] += xv.z*wv2.y;
      acc0[r] += xv.w*wv3.x; acc1[r] += xv.w*wv3.y;
    }
  }
  // f1/f2 partials, reduced over the 32 threads (one half-wave) of head h
  float a1o = a[h*128 + o],      a1o1 = a[h*128 + o + 1];
  float a2o = a[h*128 + 64 + o], a2o1 = a[h*128 + 64 + o + 1];
  float p1[16], p2[16];
  #pragma unroll
  for (int r = 0; r < 16; ++r){
    p1[r] = acc0[r]*a1o + acc1[r]*a1o1;
    p2[r] = acc0[r]*a2o + acc1[r]*a2o1;
  }
  #pragma unroll
  for (int s = 1; s <= 16; s <<= 1){
    #pragma unroll
    for (int r = 0; r < 16; ++r){
      p1[r] += __shfl_xor(p1[r], s);
      p2[r] += __shfl_xor(p2[r], s);
    }
  }
  if (g < 16){
    float f1 = 0.f, f2 = 0.f;
    #pragma unroll
    for (int r = 0; r < 16; ++r){        // static-index select (rule #20)
      f1 = (g == r) ? p1[r] : f1;
      f2 = (g == r) ? p2[r] : f2;
    }
    f1 *= L2E; f2 *= L2E;
    int base = h*N + n0 + g;
    e1p[base] = __builtin_amdgcn_exp2f(f1);
    e1n[base] = __builtin_amdgcn_exp2f(0.2f*f1);
    Tv[base]  = __builtin_amdgcn_exp2f(-f1);
    e2p[base] = __builtin_amdgcn_exp2f(f2);
    e2n[base] = __builtin_amdgcn_exp2f(0.2f*f2);
  }
  // transposed bf16 store: WhT[h][o][n]
  ushort c0[16], c1[16];
  #pragma unroll
  for (int r = 0; r < 16; ++r){ c0[r] = (ushort)bfc(acc0[r]); c1[r] = (ushort)bfc(acc1[r]); }
  ushort* d0 = WhT + ((size_t)(h*64 + o))*N + n0;
  ushort* d1 = WhT + ((size_t)(h*64 + o + 1))*N + n0;
  *(int4*)d0 = *(int4*)&c0[0]; *(int4*)(d0+8) = *(int4*)&c0[8];
  *(int4*)d1 = *(int4*)&c1[0]; *(int4*)(d1+8) = *(int4*)&c1[8];
}

// ------- fused layer-2 projection: Wh2 (bf16, transposed) + e-vectors ------
// block = 16 rows. thread: o = tid&63, rq = tid>>6 (4 rows each).
__global__ __launch_bounds__(256) void wh2f_kernel(
    const float* __restrict__ hmat, const float* __restrict__ W, const float* __restrict__ a,
    ushort* __restrict__ WhT, float* __restrict__ e1p, float* __restrict__ e1n,
    float* __restrict__ Tv, float* __restrict__ e2p, float* __restrict__ e2n){
  int n0 = blockIdx.x * 16;
  int tid = threadIdx.x;
  int o = tid & 63;
  int rq = tid >> 6;
  float acc[4] = {0.f,0.f,0.f,0.f};
  for (int f4 = 0; f4 < 128; ++f4){
    float w0 = W[(f4*4+0)*64 + o];
    float w1 = W[(f4*4+1)*64 + o];
    float w2 = W[(f4*4+2)*64 + o];
    float w3 = W[(f4*4+3)*64 + o];
    #pragma unroll
    for (int r = 0; r < 4; ++r){
      float4 xv = *(const float4*)(hmat + (size_t)(n0 + rq*4 + r)*512 + f4*4);
      acc[r] += xv.x*w0 + xv.y*w1 + xv.z*w2 + xv.w*w3;
    }
  }
  float a1o = a[o], a2o = a[64 + o];
  float p1[4], p2[4];
  #pragma unroll
  for (int r = 0; r < 4; ++r){ p1[r] = acc[r]*a1o; p2[r] = acc[r]*a2o; }
  #pragma unroll
  for (int s = 1; s <= 32; s <<= 1){
    #pragma unroll
    for (int r = 0; r < 4; ++r){
      p1[r] += __shfl_xor(p1[r], s);
      p2[r] += __shfl_xor(p2[r], s);
    }
  }
  if (o < 4){
    float f1 = 0.f, f2 = 0.f;
    #pragma unroll
    for (int r = 0; r < 4; ++r){
      f1 = (o == r) ? p1[r] : f1;
      f2 = (o == r) ? p2[r] : f2;
    }
    f1 *= L2E; f2 *= L2E;
    int base = n0 + rq*4 + o;
    e1p[base] = __builtin_amdgcn_exp2f(f1);
    e1n[base] = __builtin_amdgcn_exp2f(0.2f*f1);
    Tv[base]  = __builtin_amdgcn_exp2f(-f1);
    e2p[base] = __builtin_amdgcn_exp2f(f2);
    e2n[base] = __builtin_amdgcn_exp2f(0.2f*f2);
  }
  ushort c[4];
  #pragma unroll
  for (int r = 0; r < 4; ++r) c[r] = (ushort)bfc(acc[r]);
  ushort* d = WhT + (size_t)o*N + n0 + rq*4;
  *(uint2*)d = *(uint2*)&c[0];
}

// ---------------- MFMA masked-softmax aggregation (32x32x16) ---------------
// block = 256 thr (4 waves); output 128 n x 64 o per (h, tile, chunk).
// Double-buffered LDS B-tile, ONE barrier per m-tile, factorized exp weights.
__global__ __launch_bounds__(256) void attn_kernel(
    const ushort* __restrict__ WhT, const unsigned long long* __restrict__ bitsT,
    const float* __restrict__ e1p, const float* __restrict__ e1n, const float* __restrict__ Tv,
    const float* __restrict__ e2p, const float* __restrict__ e2n,
    float* __restrict__ num, float* __restrict__ den, int Hn, int nchunks)
{
  __shared__ ushort Bt[2][4096];   // [64 o][64 m] bf16, XOR-swizzled 16B chunks
  const int bid  = blockIdx.x;
  const int t    = bid & 31;
  const int rest = bid >> 5;
  const int h    = rest % Hn;
  const int c    = rest / Hn;
  const int n0   = t << 7;               // 128 rows per block
  const int mlen = N / nchunks;
  const int m0b  = c * mlen;
  const int tid  = threadIdx.x;
  const int w    = tid >> 6;
  const int l    = tid & 63;
  const int r32  = l & 31;
  const int kg2  = l >> 5;
  const int n    = n0 + w*32 + r32;      // this lane's output row

  const int hN = h * N;
  const float rp = e1p[hN + n];
  const float rn = e1n[hN + n];
  const float Tr = Tv[hN + n];
  const float* e2pH = e2p + hN;
  const float* e2nH = e2n + hN;
  const ushort* Wb = WhT + (size_t)h * 64 * N;

  // staging: thread stages rows so and so+32, one swizzled 16B chunk each
  const int so   = tid >> 3;             // 0..31
  const int slot = tid & 7;
  const int sc   = slot ^ (so & 7);      // source m-chunk for this slot

  // den B-fragment: column 0 = 1.0 (registers only)
  bf16x8 BD;
  #pragma unroll
  for (int j = 0; j < 8; ++j) BD[j] = (r32 == 0) ? (short)0x3F80 : (short)0;

  f32x16 acc0 = {}, acc1 = {}, accD = {};

  int4 sv0 = *(const int4*)(Wb + (size_t)so*N      + m0b + sc*8);
  int4 sv1 = *(const int4*)(Wb + (size_t)(so+32)*N + m0b + sc*8);

  #pragma unroll 1
  for (int mt = 0; mt < mlen; mt += 64){
    const int m0 = m0b + mt;
    const int buf = (mt >> 6) & 1;
    // write current staged tile (prev iter's reads of this buf long done)
    *(int4*)&Bt[buf][so*64      + slot*8] = sv0;
    *(int4*)&Bt[buf][(so+32)*64 + slot*8] = sv1;
    // issue next tile's loads (land during A-build + MFMA)
    if (mt + 64 < mlen){
      sv0 = *(const int4*)(Wb + (size_t)so*N      + m0 + 64 + sc*8);
      sv1 = *(const int4*)(Wb + (size_t)(so+32)*N + m0 + 64 + sc*8);
    }
    // ---- build A fragments: w = sel(e2p,e2n)*sel(e1p,e1n), masked ----
    unsigned long long adjw = bitsT[(size_t)(m0 >> 6)*N + n];
    bf16x8 Afr[4];
    #pragma unroll
    for (int ks = 0; ks < 4; ++ks){
      const int mo = ks*16 + kg2*8;
      const float* pp = e2pH + m0 + mo;
      const float* pn = e2nH + m0 + mo;
      f32x4 pa = *(const f32x4*)pp;
      f32x4 pb = *(const f32x4*)(pp + 4);
      f32x4 qa = *(const f32x4*)pn;
      f32x4 qb = *(const f32x4*)(pn + 4);
      uint32_t bb = (uint32_t)(adjw >> mo) & 0xFFu;
      bf16x8 A;
      #pragma unroll
      for (int j = 0; j < 4; ++j){
        bool c0 = pa[j] > Tr;
        float w0 = (c0 ? pa[j] : qa[j]) * (c0 ? rp : rn);
        w0 = ((bb >> j) & 1u) ? w0 : 0.f;
        bool c1 = pb[j] > Tr;
        float w1 = (c1 ? pb[j] : qb[j]) * (c1 ? rp : rn);
        w1 = ((bb >> (4+j)) & 1u) ? w1 : 0.f;
        A[j]   = bfc(w0);
        A[4+j] = bfc(w1);
      }
      Afr[ks] = A;
    }
    __syncthreads();                     // all ds_writes of this buf visible
    // ---- MFMA: 4 k-steps x (2 col-blocks + den) ----
    #pragma unroll
    for (int ks = 0; ks < 4; ++ks){
      const int ci = ks*2 + kg2;
      const int sw = (ci ^ (r32 & 7)) << 3;
      bf16x8 B0 = *(const bf16x8*)&Bt[buf][ r32      *64 + sw];
      bf16x8 B1 = *(const bf16x8*)&Bt[buf][(32 + r32)*64 + sw];
      acc0 = __builtin_amdgcn_mfma_f32_32x32x16_bf16(Afr[ks], B0, acc0, 0, 0, 0);
      acc1 = __builtin_amdgcn_mfma_f32_32x32x16_bf16(Afr[ks], B1, acc1, 0, 0, 0);
      accD = __builtin_amdgcn_mfma_f32_32x32x16_bf16(Afr[ks], BD, accD, 0, 0, 0);
    }
  }

  // ---- write num (C/D map: col = l&31, row = (r&3)+8*(r>>2)+4*kg2) ----
  float* nb = num + ((size_t)(c*Hn + h)*N + n0 + w*32)*64;
  #pragma unroll
  for (int r = 0; r < 16; ++r){
    int row = (r & 3) + 8*(r >> 2) + 4*kg2;
    nb[(size_t)row*64 +      r32] = acc0[r];
    nb[(size_t)row*64 + 32 + r32] = acc1[r];
  }
  if (r32 == 0){
    float* db = den + (size_t)(c*Hn + h)*N + n0 + w*32;
    #pragma unroll
    for (int r = 0; r < 16; ++r){
      int row = (r & 3) + 8*(r >> 2) + 4*kg2;
      db[row] = accD[r];
    }
  }
}

// ---------------- finalize layer 1: hmat = elu(sum num / sum den) ----------
__global__ __launch_bounds__(256) void fin1_kernel(const float* __restrict__ num,
                                                   const float* __restrict__ den,
                                                   float* __restrict__ hmat, int nch){
  int idx4 = blockIdx.x * 256 + threadIdx.x;    // over 8*N*64/4 = 524288
  int o4 = idx4 & 15;
  int hn = idx4 >> 4;
  int n = hn & (N - 1);
  int h = hn >> 12;
  const f32x4* num4 = (const f32x4*)num;
  f32x4 nu = {};
  float de = 0.f;
  for (int cc = 0; cc < nch; ++cc){
    nu += num4[(size_t)cc*(8*N*16) + (size_t)hn*16 + o4];
    de += den[(size_t)cc*(8*N) + hn];
  }
  float inv = 1.f / de;
  f32x4 r;
  #pragma unroll
  for (int j = 0; j < 4; ++j) r[j] = elu_f(nu[j] * inv);
  *(f32x4*)(hmat + (size_t)n*512 + h*64 + o4*4) = r;
}

// ---------------- finalize layer 2: out = elu(sum num / sum den) -----------
__global__ __launch_bounds__(256) void fin2_kernel(const float* __restrict__ num,
                                                   const float* __restrict__ den,
                                                   float* __restrict__ out, int nch){
  int idx4 = blockIdx.x * 256 + threadIdx.x;    // over N*64/4 = 65536
  int n = idx4 >> 4;
  const f32x4* num4 = (const f32x4*)num;
  f32x4 s = {};
  float d = 0.f;
  for (int cc = 0; cc < nch; ++cc){
    s += num4[(size_t)cc*(N*16) + idx4];
    d += den[(size_t)cc*N + n];
  }
  float inv = 1.f / d;
  f32x4 r;
  #pragma unroll
  for (int j = 0; j < 4; ++j) r[j] = elu_f(s[j] * inv);
  *(f32x4*)(out + (size_t)idx4*4) = r;
}

extern "C" void kernel_launch(void* const* d_in, const int* in_sizes, int n_in,
                              void* d_out, int out_size, void* d_ws, size_t ws_size,
                              hipStream_t stream){
  const float* x       = (const float*)d_in[0];
  const int*   adj     = (const int*)d_in[1];
  const float* W_heads = (const float*)d_in[3];
  const float* a_heads = (const float*)d_in[4];
  const float* W_out   = (const float*)d_in[5];
  const float* a_out   = (const float*)d_in[6];
  float* out = (float*)d_out;
  char* ws = (char*)d_ws;

  const size_t MB = 1u << 20;
  const size_t KB = 1u << 10;
  // layout (48 MB total):
  // 0-2    bitsT | 2-6 Wh1T (reused as Wh2T) | 6-6.625 e1 arrays (5x128KB)
  // 6.75-  e2 arrays (5x16KB) | 7.0-7.5 den1 | 7.5-7.75 den2
  // 8-16   hmat | 16-48 num1 (nch1 x 8MB); num2 (16x1MB) reuses 16-32
  unsigned long long* bitsT = (unsigned long long*)(ws);
  ushort* Wh1T = (ushort*)(ws + 2*MB);
  ushort* Wh2T = (ushort*)(ws + 2*MB);
  float* e1p1 = (float*)(ws + 6*MB);
  float* e1n1 = (float*)(ws + 6*MB + 128*KB);
  float* Tv1  = (float*)(ws + 6*MB + 256*KB);
  float* e2p1 = (float*)(ws + 6*MB + 384*KB);
  float* e2n1 = (float*)(ws + 6*MB + 512*KB);
  float* e1p2 = (float*)(ws + 6*MB + 768*KB);
  float* e1n2 = (float*)(ws + 6*MB + 784*KB);
  float* Tv2  = (float*)(ws + 6*MB + 800*KB);
  float* e2p2 = (float*)(ws + 6*MB + 816*KB);
  float* e2n2 = (float*)(ws + 6*MB + 832*KB);
  float* den1 = (float*)(ws + 7*MB);
  float* den2 = (float*)(ws + 7*MB + 512*KB);
  float* hmat = (float*)(ws + 8*MB);
  float* num1 = (float*)(ws + 16*MB);
  float* num2 = num1;

  const int nch1 = (ws_size >= (size_t)48*MB) ? 4 : 2;
  const int nch2 = 16;

  mask_kernel<<<1024, 256, 0, stream>>>(adj, bitsT);
  wh1f_kernel<<<256, 256, 0, stream>>>(x, W_heads, a_heads, Wh1T, e1p1, e1n1, Tv1, e2p1, e2n1);
  attn_kernel<<<32*8*nch1, 256, 0, stream>>>(Wh1T, bitsT, e1p1, e1n1, Tv1, e2p1, e2n1,
                                             num1, den1, 8, nch1);
  fin1_kernel<<<2048, 256, 0, stream>>>(num1, den1, hmat, nch1);
  wh2f_kernel<<<256, 256, 0, stream>>>(hmat, W_out, a_out, Wh2T, e1p2, e1n2, Tv2, e2p2, e2n2);
  attn_kernel<<<32*1*16, 256, 0, stream>>>(Wh2T, bitsT, e1p2, e1n2, Tv2, e2p2, e2n2,
                                           num2, den2, 1, nch2);
  fin2_kernel<<<256, 256, 0, stream>>>(num2, den2, out, nch2);
}

// Round 7
// 145.051 us; speedup vs baseline: 1.2120x; 1.0677x over previous
//
#include <hip/hip_runtime.h>
#include <hip/hip_bf16.h>
#include <cstdint>

#define N 4096
#define L2E 1.44269504088896f

typedef __attribute__((ext_vector_type(8))) short bf16x8;
typedef __attribute__((ext_vector_type(4))) float f32x4;
typedef __attribute__((ext_vector_type(16))) float f32x16;

__device__ __forceinline__ float elu_f(float x){ return x > 0.f ? x : __expf(x) - 1.f; }
__device__ __forceinline__ short bfc(float x){
  __hip_bfloat16 h = __float2bfloat16(x);
  return *reinterpret_cast<short*>(&h);
}

// ---------------- adj -> transposed bitmask: bitsT[word][n] ----------------
__global__ __launch_bounds__(256) void mask_kernel(const int* __restrict__ adj,
                                                   unsigned long long* __restrict__ bitsT){
  int gwave = (blockIdx.x * blockDim.x + threadIdx.x) >> 6;
  int lane = threadIdx.x & 63;
  if (gwave >= N) return;
  const int* arow = adj + (size_t)gwave * N;
  #pragma unroll 8
  for (int w = 0; w < 64; ++w){
    unsigned long long b = __ballot(arow[(w << 6) + lane] != 0);
    if (lane == 0) bitsT[(size_t)w * N + gwave] = b;
  }
}

// ------- fused layer-1 projection: Wh (bf16, transposed) + e-vectors -------
__global__ __launch_bounds__(256) void wh1f_kernel(
    const float* __restrict__ x, const float* __restrict__ W, const float* __restrict__ a,
    ushort* __restrict__ WhT, float* __restrict__ e1p, float* __restrict__ e1n,
    float* __restrict__ e2p, float* __restrict__ e2n){
  int n0 = blockIdx.x * 16;
  int tid = threadIdx.x;
  int h = tid >> 5;
  int g = tid & 31;
  int o = g * 2;
  const float* Wp = W + h * 8192 + o;
  float acc0[16], acc1[16];
  #pragma unroll
  for (int r = 0; r < 16; ++r){ acc0[r] = 0.f; acc1[r] = 0.f; }
  for (int f4 = 0; f4 < 32; ++f4){
    float2 wv0 = *(const float2*)(Wp + (f4*4+0)*64);
    float2 wv1 = *(const float2*)(Wp + (f4*4+1)*64);
    float2 wv2 = *(const float2*)(Wp + (f4*4+2)*64);
    float2 wv3 = *(const float2*)(Wp + (f4*4+3)*64);
    #pragma unroll
    for (int r = 0; r < 16; ++r){
      float4 xv = *(const float4*)(x + (size_t)(n0 + r)*128 + f4*4);
      acc0[r] += xv.x*wv0.x; acc1[r] += xv.x*wv0.y;
      acc0[r] += xv.y*wv1.x; acc1[r] += xv.y*wv1.y;
      acc0[r] += xv.z*wv2.x; acc1[r] += xv.z*wv2.y;
      acc0[r] += xv.w*wv3.x; acc1[r] += xv.w*wv3.y;
    }
  }
  float a1o = a[h*128 + o],      a1o1 = a[h*128 + o + 1];
  float a2o = a[h*128 + 64 + o], a2o1 = a[h*128 + 64 + o + 1];
  float p1[16], p2[16];
  #pragma unroll
  for (int r = 0; r < 16; ++r){
    p1[r] = acc0[r]*a1o + acc1[r]*a1o1;
    p2[r] = acc0[r]*a2o + acc1[r]*a2o1;
  }
  #pragma unroll
  for (int s = 1; s <= 16; s <<= 1){
    #pragma unroll
    for (int r = 0; r < 16; ++r){
      p1[r] += __shfl_xor(p1[r], s);
      p2[r] += __shfl_xor(p2[r], s);
    }
  }
  if (g < 16){
    float f1 = 0.f, f2 = 0.f;
    #pragma unroll
    for (int r = 0; r < 16; ++r){
      f1 = (g == r) ? p1[r] : f1;
      f2 = (g == r) ? p2[r] : f2;
    }
    f1 *= L2E; f2 *= L2E;
    int base = h*N + n0 + g;
    e1p[base] = __builtin_amdgcn_exp2f(f1);
    e1n[base] = __builtin_amdgcn_exp2f(0.2f*f1);
    e2p[base] = __builtin_amdgcn_exp2f(f2);
    e2n[base] = __builtin_amdgcn_exp2f(0.2f*f2);
  }
  ushort c0[16], c1[16];
  #pragma unroll
  for (int r = 0; r < 16; ++r){ c0[r] = (ushort)bfc(acc0[r]); c1[r] = (ushort)bfc(acc1[r]); }
  ushort* d0 = WhT + ((size_t)(h*64 + o))*N + n0;
  ushort* d1 = WhT + ((size_t)(h*64 + o + 1))*N + n0;
  *(int4*)d0 = *(int4*)&c0[0]; *(int4*)(d0+8) = *(int4*)&c0[8];
  *(int4*)d1 = *(int4*)&c1[0]; *(int4*)(d1+8) = *(int4*)&c1[8];
}

// ------- fused: fin1 (num/den->elu in LDS) + layer-2 projection ------------
__global__ __launch_bounds__(256) void wh2f_kernel(
    const float* __restrict__ num, const float* __restrict__ den,
    const float* __restrict__ W, const float* __restrict__ a,
    ushort* __restrict__ WhT, float* __restrict__ e1p, float* __restrict__ e1n,
    float* __restrict__ e2p, float* __restrict__ e2n, int nch){
  __shared__ float hm[16][512];
  __shared__ float dinv[128];
  int n0 = blockIdx.x * 16;
  int tid = threadIdx.x;
  // phase 0: per-(h,row) inverse denominators
  if (tid < 128){
    int h = tid >> 4, r = tid & 15;
    float de = 0.f;
    for (int cc = 0; cc < nch; ++cc)
      de += den[(size_t)(cc*8 + h)*N + n0 + r];
    dinv[tid] = 1.f / de;
  }
  __syncthreads();
  // phase 1: hm[r][h*64+o] = elu(sum num / den)
  const f32x4* num4 = (const f32x4*)num;
  #pragma unroll
  for (int e = 0; e < 8; ++e){
    int idx4 = tid + e*256;          // over 16 rows x 128 float4-cols
    int r = idx4 >> 7;
    int c4 = idx4 & 127;
    int h = c4 >> 4;
    int o4 = c4 & 15;
    f32x4 nu = {};
    for (int cc = 0; cc < nch; ++cc)
      nu += num4[((size_t)(cc*8 + h)*N + n0 + r)*16 + o4];
    float inv = dinv[h*16 + r];
    f32x4 v;
    #pragma unroll
    for (int j = 0; j < 4; ++j) v[j] = elu_f(nu[j] * inv);
    *(f32x4*)&hm[r][c4*4] = v;
  }
  __syncthreads();
  // phase 2: Wh2 = hm(16x512) . W(512x64), + f-vectors
  int o = tid & 63;
  int rq = tid >> 6;
  float acc[4] = {0.f,0.f,0.f,0.f};
  for (int f4 = 0; f4 < 128; ++f4){
    float w0 = W[(f4*4+0)*64 + o];
    float w1 = W[(f4*4+1)*64 + o];
    float w2 = W[(f4*4+2)*64 + o];
    float w3 = W[(f4*4+3)*64 + o];
    #pragma unroll
    for (int r = 0; r < 4; ++r){
      float4 xv = *(const float4*)&hm[rq*4 + r][f4*4];
      acc[r] += xv.x*w0 + xv.y*w1 + xv.z*w2 + xv.w*w3;
    }
  }
  float a1o = a[o], a2o = a[64 + o];
  float p1[4], p2[4];
  #pragma unroll
  for (int r = 0; r < 4; ++r){ p1[r] = acc[r]*a1o; p2[r] = acc[r]*a2o; }
  #pragma unroll
  for (int s = 1; s <= 32; s <<= 1){
    #pragma unroll
    for (int r = 0; r < 4; ++r){
      p1[r] += __shfl_xor(p1[r], s);
      p2[r] += __shfl_xor(p2[r], s);
    }
  }
  if (o < 4){
    float f1 = 0.f, f2 = 0.f;
    #pragma unroll
    for (int r = 0; r < 4; ++r){
      f1 = (o == r) ? p1[r] : f1;
      f2 = (o == r) ? p2[r] : f2;
    }
    f1 *= L2E; f2 *= L2E;
    int base = n0 + rq*4 + o;
    e1p[base] = __builtin_amdgcn_exp2f(f1);
    e1n[base] = __builtin_amdgcn_exp2f(0.2f*f1);
    e2p[base] = __builtin_amdgcn_exp2f(f2);
    e2n[base] = __builtin_amdgcn_exp2f(0.2f*f2);
  }
  ushort c[4];
  #pragma unroll
  for (int r = 0; r < 4; ++r) c[r] = (ushort)bfc(acc[r]);
  ushort* d = WhT + (size_t)o*N + n0 + rq*4;
  *(uint2*)d = *(uint2*)&c[0];
}

// ---------------- MFMA masked-softmax aggregation (32x32x16) ---------------
// block = 256 thr (4 waves); output 128 n x 64 o per (h, tile, chunk).
// Double-buffered Bt + Et, ONE barrier per tile, max-trick weights,
// e2/adj prefetched a full tile ahead.
__global__ __launch_bounds__(256) void attn_kernel(
    const ushort* __restrict__ WhT, const unsigned long long* __restrict__ bitsT,
    const float* __restrict__ e1p, const float* __restrict__ e1n,
    const float* __restrict__ e2p, const float* __restrict__ e2n,
    float* __restrict__ num, float* __restrict__ den, int Hn, int nchunks)
{
  __shared__ ushort Bt[2][4096];   // [64 o][64 m] bf16, XOR-swizzled 16B chunks
  __shared__ float  Et[2][128];    // [e2p 64][e2n 64] for current m-tile
  const int bid  = blockIdx.x;
  const int t    = bid & 31;
  const int rest = bid >> 5;
  const int h    = rest % Hn;
  const int c    = rest / Hn;
  const int n0   = t << 7;
  const int mlen = N / nchunks;
  const int m0b  = c * mlen;
  const int tid  = threadIdx.x;
  const int w    = tid >> 6;
  const int l    = tid & 63;
  const int r32  = l & 31;
  const int kg2  = l >> 5;
  const int n    = n0 + w*32 + r32;

  const int hN = h * N;
  const float rp = e1p[hN + n];
  const float rn = e1n[hN + n];
  const ushort* Wb = WhT + (size_t)h * 64 * N;

  const int so   = tid >> 3;
  const int slot = tid & 7;
  const int sc   = slot ^ (so & 7);
  const float* evsrc = ((tid < 16) ? (e2p + hN) : (e2n + hN)) + ((tid & 15) << 2);

  bf16x8 BD;
  #pragma unroll
  for (int j = 0; j < 8; ++j) BD[j] = (r32 == 0) ? (short)0x3F80 : (short)0;

  f32x16 acc0 = {}, acc1 = {}, accD = {};

  // prologue: prefetch tile 0
  int4 sv0 = *(const int4*)(Wb + (size_t)so*N      + m0b + sc*8);
  int4 sv1 = *(const int4*)(Wb + (size_t)(so+32)*N + m0b + sc*8);
  f32x4 ev = {};
  if (tid < 32) ev = *(const f32x4*)(evsrc + m0b);
  unsigned long long aw = bitsT[(size_t)(m0b >> 6)*N + n];

  #pragma unroll 1
  for (int mt = 0; mt < mlen; mt += 64){
    const int m0 = m0b + mt;
    const int buf = (mt >> 6) & 1;
    const unsigned long long adjw = aw;
    // ---- write staged tile (regs from previous iteration) ----
    *(int4*)&Bt[buf][so*64      + slot*8] = sv0;
    *(int4*)&Bt[buf][(so+32)*64 + slot*8] = sv1;
    if (tid < 32) *(f32x4*)&Et[buf][tid << 2] = ev;
    // ---- prefetch next tile ----
    if (mt + 64 < mlen){
      sv0 = *(const int4*)(Wb + (size_t)so*N      + m0 + 64 + sc*8);
      sv1 = *(const int4*)(Wb + (size_t)(so+32)*N + m0 + 64 + sc*8);
      if (tid < 32) ev = *(const f32x4*)(evsrc + m0 + 64);
      aw = bitsT[(size_t)((m0 + 64) >> 6)*N + n];
    }
    __syncthreads();                 // Bt/Et of buf visible
    // ---- A-build: w = max(e2p*e1p, e2n*e1n), masked ----
    const float* Eb = &Et[buf][0];
    bf16x8 Afr[4];
    #pragma unroll
    for (int ks = 0; ks < 4; ++ks){
      const int mo = ks*16 + kg2*8;
      f32x4 pa = *(const f32x4*)&Eb[mo];
      f32x4 pb = *(const f32x4*)&Eb[mo + 4];
      f32x4 qa = *(const f32x4*)&Eb[64 + mo];
      f32x4 qb = *(const f32x4*)&Eb[64 + mo + 4];
      uint32_t bb = (uint32_t)(adjw >> mo) & 0xFFu;
      bf16x8 A;
      #pragma unroll
      for (int j = 0; j < 4; ++j){
        float w0 = fmaxf(pa[j]*rp, qa[j]*rn);
        w0 = (bb & (1u << j))     ? w0 : 0.f;
        float w1 = fmaxf(pb[j]*rp, qb[j]*rn);
        w1 = (bb & (1u << (4+j))) ? w1 : 0.f;
        A[j]   = bfc(w0);
        A[4+j] = bfc(w1);
      }
      Afr[ks] = A;
    }
    // ---- MFMA: 4 k-steps x (2 col-blocks + den) ----
    #pragma unroll
    for (int ks = 0; ks < 4; ++ks){
      const int ci = ks*2 + kg2;
      const int sw = (ci ^ (r32 & 7)) << 3;
      bf16x8 B0 = *(const bf16x8*)&Bt[buf][ r32      *64 + sw];
      bf16x8 B1 = *(const bf16x8*)&Bt[buf][(32 + r32)*64 + sw];
      acc0 = __builtin_amdgcn_mfma_f32_32x32x16_bf16(Afr[ks], B0, acc0, 0, 0, 0);
      acc1 = __builtin_amdgcn_mfma_f32_32x32x16_bf16(Afr[ks], B1, acc1, 0, 0, 0);
      accD = __builtin_amdgcn_mfma_f32_32x32x16_bf16(Afr[ks], BD, accD, 0, 0, 0);
    }
  }

  float* nb = num + ((size_t)(c*Hn + h)*N + n0 + w*32)*64;
  #pragma unroll
  for (int r = 0; r < 16; ++r){
    int row = (r & 3) + 8*(r >> 2) + 4*kg2;
    nb[(size_t)row*64 +      r32] = acc0[r];
    nb[(size_t)row*64 + 32 + r32] = acc1[r];
  }
  if (r32 == 0){
    float* db = den + (size_t)(c*Hn + h)*N + n0 + w*32;
    #pragma unroll
    for (int r = 0; r < 16; ++r){
      int row = (r & 3) + 8*(r >> 2) + 4*kg2;
      db[row] = accD[r];
    }
  }
}

// ---------------- finalize layer 2: out = elu(sum num / sum den) -----------
__global__ __launch_bounds__(256) void fin2_kernel(const float* __restrict__ num,
                                                   const float* __restrict__ den,
                                                   float* __restrict__ out, int nch){
  int idx4 = blockIdx.x * 256 + threadIdx.x;    // over N*64/4 = 65536
  int n = idx4 >> 4;
  const f32x4* num4 = (const f32x4*)num;
  f32x4 s = {};
  float d = 0.f;
  for (int cc = 0; cc < nch; ++cc){
    s += num4[(size_t)cc*(N*16) + idx4];
    d += den[(size_t)cc*N + n];
  }
  float inv = 1.f / d;
  f32x4 r;
  #pragma unroll
  for (int j = 0; j < 4; ++j) r[j] = elu_f(s[j] * inv);
  *(f32x4*)(out + (size_t)idx4*4) = r;
}

extern "C" void kernel_launch(void* const* d_in, const int* in_sizes, int n_in,
                              void* d_out, int out_size, void* d_ws, size_t ws_size,
                              hipStream_t stream){
  const float* x       = (const float*)d_in[0];
  const int*   adj     = (const int*)d_in[1];
  const float* W_heads = (const float*)d_in[3];
  const float* a_heads = (const float*)d_in[4];
  const float* W_out   = (const float*)d_in[5];
  const float* a_out   = (const float*)d_in[6];
  float* out = (float*)d_out;
  char* ws = (char*)d_ws;

  const size_t MB = 1u << 20;
  const size_t KB = 1u << 10;
  // layout:
  // 0-2MB bitsT | 2-6 Wh1T (Wh2T overlays after attn1) | 6-6.5 L1 e-vecs (4x128KB)
  // 6.5-6.6 L2 e-vecs (4x16KB) | 7-8 den1 | 8-8.25 den2
  // 9..9+nch1*8MB num1 ; num2 (16x1MB) reuses 9-25MB
  unsigned long long* bitsT = (unsigned long long*)(ws);
  ushort* Wh1T = (ushort*)(ws + 2*MB);
  ushort* Wh2T = (ushort*)(ws + 2*MB);
  float* e1p1 = (float*)(ws + 6*MB);
  float* e1n1 = (float*)(ws + 6*MB + 128*KB);
  float* e2p1 = (float*)(ws + 6*MB + 256*KB);
  float* e2n1 = (float*)(ws + 6*MB + 384*KB);
  float* e1p2 = (float*)(ws + 6*MB + 512*KB);
  float* e1n2 = (float*)(ws + 6*MB + 528*KB);
  float* e2p2 = (float*)(ws + 6*MB + 544*KB);
  float* e2n2 = (float*)(ws + 6*MB + 560*KB);
  float* den1 = (float*)(ws + 7*MB);
  float* den2 = (float*)(ws + 8*MB);
  float* num1 = (float*)(ws + 9*MB);
  float* num2 = num1;

  const int nch1 = (ws_size >= (size_t)73*MB) ? 8 : (ws_size >= (size_t)41*MB) ? 4 : 2;
  const int nch2 = 16;

  mask_kernel<<<1024, 256, 0, stream>>>(adj, bitsT);
  wh1f_kernel<<<256, 256, 0, stream>>>(x, W_heads, a_heads, Wh1T, e1p1, e1n1, e2p1, e2n1);
  attn_kernel<<<32*8*nch1, 256, 0, stream>>>(Wh1T, bitsT, e1p1, e1n1, e2p1, e2n1,
                                             num1, den1, 8, nch1);
  wh2f_kernel<<<256, 256, 0, stream>>>(num1, den1, W_out, a_out, Wh2T,
                                       e1p2, e1n2, e2p2, e2n2, nch1);
  attn_kernel<<<32*1*nch2, 256, 0, stream>>>(Wh2T, bitsT, e1p2, e1n2, e2p2, e2n2,
                                             num2, den2, 1, nch2);
  fin2_kernel<<<256, 256, 0, stream>>>(num2, den2, out, nch2);
}

// Round 9
// 137.492 us; speedup vs baseline: 1.2787x; 1.0550x over previous
//
#include <hip/hip_runtime.h>
#include <hip/hip_bf16.h>
#include <cstdint>

#define N 4096
#define L2E 1.44269504088896f

typedef __attribute__((ext_vector_type(2))) __fp16 fp16x2;
typedef __attribute__((ext_vector_type(8))) _Float16 half8;
typedef __attribute__((ext_vector_type(4))) float f32x4;
typedef __attribute__((ext_vector_type(16))) float f32x16;

__device__ __forceinline__ float elu_f(float x){ return x > 0.f ? x : __expf(x) - 1.f; }

// ---------------- adj -> transposed bitmask: bitsT[word][n] ----------------
__global__ __launch_bounds__(256) void mask_kernel(const int* __restrict__ adj,
                                                   unsigned long long* __restrict__ bitsT){
  int gwave = (blockIdx.x * blockDim.x + threadIdx.x) >> 6;
  int lane = threadIdx.x & 63;
  if (gwave >= N) return;
  const int* arow = adj + (size_t)gwave * N;
  #pragma unroll 8
  for (int w = 0; w < 64; ++w){
    unsigned long long b = __ballot(arow[(w << 6) + lane] != 0);
    if (lane == 0) bitsT[(size_t)w * N + gwave] = b;
  }
}

// ------- fused layer-1 projection: Wh (fp16, transposed) + e-vectors -------
// e1p/e1n carry a per-row 2^-k renorm (k = rint(f1*L2E)) that cancels in
// num/den but keeps all fp16 products bounded.
__global__ __launch_bounds__(256) void wh1f_kernel(
    const float* __restrict__ x, const float* __restrict__ W, const float* __restrict__ a,
    ushort* __restrict__ WhT, float* __restrict__ e1p, float* __restrict__ e1n,
    float* __restrict__ e2p, float* __restrict__ e2n){
  int n0 = blockIdx.x * 16;
  int tid = threadIdx.x;
  int h = tid >> 5;
  int g = tid & 31;
  int o = g * 2;
  const float* Wp = W + h * 8192 + o;
  float acc0[16], acc1[16];
  #pragma unroll
  for (int r = 0; r < 16; ++r){ acc0[r] = 0.f; acc1[r] = 0.f; }
  for (int f4 = 0; f4 < 32; ++f4){
    float2 wv0 = *(const float2*)(Wp + (f4*4+0)*64);
    float2 wv1 = *(const float2*)(Wp + (f4*4+1)*64);
    float2 wv2 = *(const float2*)(Wp + (f4*4+2)*64);
    float2 wv3 = *(const float2*)(Wp + (f4*4+3)*64);
    #pragma unroll
    for (int r = 0; r < 16; ++r){
      float4 xv = *(const float4*)(x + (size_t)(n0 + r)*128 + f4*4);
      acc0[r] += xv.x*wv0.x; acc1[r] += xv.x*wv0.y;
      acc0[r] += xv.y*wv1.x; acc1[r] += xv.y*wv1.y;
      acc0[r] += xv.z*wv2.x; acc1[r] += xv.z*wv2.y;
      acc0[r] += xv.w*wv3.x; acc1[r] += xv.w*wv3.y;
    }
  }
  float a1o = a[h*128 + o],      a1o1 = a[h*128 + o + 1];
  float a2o = a[h*128 + 64 + o], a2o1 = a[h*128 + 64 + o + 1];
  float p1[16], p2[16];
  #pragma unroll
  for (int r = 0; r < 16; ++r){
    p1[r] = acc0[r]*a1o + acc1[r]*a1o1;
    p2[r] = acc0[r]*a2o + acc1[r]*a2o1;
  }
  #pragma unroll
  for (int s = 1; s <= 16; s <<= 1){
    #pragma unroll
    for (int r = 0; r < 16; ++r){
      p1[r] += __shfl_xor(p1[r], s);
      p2[r] += __shfl_xor(p2[r], s);
    }
  }
  if (g < 16){
    float f1 = 0.f, f2 = 0.f;
    #pragma unroll
    for (int r = 0; r < 16; ++r){
      f1 = (g == r) ? p1[r] : f1;
      f2 = (g == r) ? p2[r] : f2;
    }
    f1 *= L2E; f2 *= L2E;
    float k = rintf(f1);
    int base = h*N + n0 + g;
    e1p[base] = __builtin_amdgcn_exp2f(f1 - k);
    e1n[base] = __builtin_amdgcn_exp2f(0.2f*f1 - k);
    e2p[base] = __builtin_amdgcn_exp2f(f2);
    e2n[base] = __builtin_amdgcn_exp2f(0.2f*f2);
  }
  union { fp16x2 d[8]; int4 q[2]; } pc0, pc1;
  #pragma unroll
  for (int r = 0; r < 8; ++r){
    pc0.d[r] = __builtin_amdgcn_cvt_pkrtz(acc0[2*r], acc0[2*r+1]);
    pc1.d[r] = __builtin_amdgcn_cvt_pkrtz(acc1[2*r], acc1[2*r+1]);
  }
  ushort* d0 = WhT + ((size_t)(h*64 + o))*N + n0;
  ushort* d1 = WhT + ((size_t)(h*64 + o + 1))*N + n0;
  *(int4*)d0 = pc0.q[0]; *(int4*)(d0+8) = pc0.q[1];
  *(int4*)d1 = pc1.q[0]; *(int4*)(d1+8) = pc1.q[1];
}

// ------- fused: fin1 (num/den->elu in LDS) + layer-2 projection ------------
__global__ __launch_bounds__(256) void wh2f_kernel(
    const float* __restrict__ num, const float* __restrict__ den,
    const float* __restrict__ W, const float* __restrict__ a,
    ushort* __restrict__ WhT, float* __restrict__ e1p, float* __restrict__ e1n,
    float* __restrict__ e2p, float* __restrict__ e2n, int nch){
  __shared__ float hm[16][512];
  __shared__ float dinv[128];
  int n0 = blockIdx.x * 16;
  int tid = threadIdx.x;
  if (tid < 128){
    int h = tid >> 4, r = tid & 15;
    float de = 0.f;
    for (int cc = 0; cc < nch; ++cc)
      de += den[(size_t)(cc*8 + h)*N + n0 + r];
    dinv[tid] = 1.f / de;
  }
  __syncthreads();
  const f32x4* num4 = (const f32x4*)num;
  #pragma unroll
  for (int e = 0; e < 8; ++e){
    int idx4 = tid + e*256;
    int r = idx4 >> 7;
    int c4 = idx4 & 127;
    int h = c4 >> 4;
    int o4 = c4 & 15;
    f32x4 nu = {};
    for (int cc = 0; cc < nch; ++cc)
      nu += num4[((size_t)(cc*8 + h)*N + n0 + r)*16 + o4];
    float inv = dinv[h*16 + r];
    f32x4 v;
    #pragma unroll
    for (int j = 0; j < 4; ++j) v[j] = elu_f(nu[j] * inv);
    *(f32x4*)&hm[r][c4*4] = v;
  }
  __syncthreads();
  int o = tid & 63;
  int rq = tid >> 6;
  float acc[4] = {0.f,0.f,0.f,0.f};
  for (int f4 = 0; f4 < 128; ++f4){
    float w0 = W[(f4*4+0)*64 + o];
    float w1 = W[(f4*4+1)*64 + o];
    float w2 = W[(f4*4+2)*64 + o];
    float w3 = W[(f4*4+3)*64 + o];
    #pragma unroll
    for (int r = 0; r < 4; ++r){
      float4 xv = *(const float4*)&hm[rq*4 + r][f4*4];
      acc[r] += xv.x*w0 + xv.y*w1 + xv.z*w2 + xv.w*w3;
    }
  }
  float a1o = a[o], a2o = a[64 + o];
  float p1[4], p2[4];
  #pragma unroll
  for (int r = 0; r < 4; ++r){ p1[r] = acc[r]*a1o; p2[r] = acc[r]*a2o; }
  #pragma unroll
  for (int s = 1; s <= 32; s <<= 1){
    #pragma unroll
    for (int r = 0; r < 4; ++r){
      p1[r] += __shfl_xor(p1[r], s);
      p2[r] += __shfl_xor(p2[r], s);
    }
  }
  if (o < 4){
    float f1 = 0.f, f2 = 0.f;
    #pragma unroll
    for (int r = 0; r < 4; ++r){
      f1 = (o == r) ? p1[r] : f1;
      f2 = (o == r) ? p2[r] : f2;
    }
    f1 *= L2E; f2 *= L2E;
    float k = rintf(f1);
    int base = n0 + rq*4 + o;
    e1p[base] = __builtin_amdgcn_exp2f(f1 - k);
    e1n[base] = __builtin_amdgcn_exp2f(0.2f*f1 - k);
    e2p[base] = __builtin_amdgcn_exp2f(f2);
    e2n[base] = __builtin_amdgcn_exp2f(0.2f*f2);
  }
  union { fp16x2 d[2]; uint2 q; } pc;
  pc.d[0] = __builtin_amdgcn_cvt_pkrtz(acc[0], acc[1]);
  pc.d[1] = __builtin_amdgcn_cvt_pkrtz(acc[2], acc[3]);
  ushort* d = WhT + (size_t)o*N + n0 + rq*4;
  *(uint2*)d = pc.q;
}

// ---------------- MFMA masked-softmax aggregation (32x32x16 fp16) ----------
// block = 256 thr (4 waves); output 128 n x 64 o per (h, tile, chunk).
// Double-buffered Bt + Et, ONE barrier per tile, max-trick weights,
// e2/adj prefetched a full tile ahead, hardware cvt_pkrtz packing.
__global__ __launch_bounds__(256) void attn_kernel(
    const ushort* __restrict__ WhT, const unsigned long long* __restrict__ bitsT,
    const float* __restrict__ e1p, const float* __restrict__ e1n,
    const float* __restrict__ e2p, const float* __restrict__ e2n,
    float* __restrict__ num, float* __restrict__ den, int Hn, int nchunks)
{
  __shared__ ushort Bt[2][4096];   // [64 o][64 m] fp16, XOR-swizzled 16B chunks
  __shared__ float  Et[2][128];    // [e2p 64][e2n 64] for current m-tile
  const int bid  = blockIdx.x;
  const int t    = bid & 31;
  const int rest = bid >> 5;
  const int h    = rest % Hn;
  const int c    = rest / Hn;
  const int n0   = t << 7;
  const int mlen = N / nchunks;
  const int m0b  = c * mlen;
  const int tid  = threadIdx.x;
  const int w    = tid >> 6;
  const int l    = tid & 63;
  const int r32  = l & 31;
  const int kg2  = l >> 5;
  const int n    = n0 + w*32 + r32;

  const int hN = h * N;
  const float rp = e1p[hN + n];
  const float rn = e1n[hN + n];
  const ushort* Wb = WhT + (size_t)h * 64 * N;

  const int so   = tid >> 3;
  const int slot = tid & 7;
  const int sc   = slot ^ (so & 7);
  const float* evsrc = ((tid < 16) ? (e2p + hN) : (e2n + hN)) + ((tid & 15) << 2);

  half8 BD = {};
  if (r32 == 0){
    #pragma unroll
    for (int j = 0; j < 8; ++j) BD[j] = (_Float16)1.f;
  }

  f32x16 acc0 = {}, acc1 = {}, accD = {};

  // prologue: prefetch tile 0
  int4 sv0 = *(const int4*)(Wb + (size_t)so*N      + m0b + sc*8);
  int4 sv1 = *(const int4*)(Wb + (size_t)(so+32)*N + m0b + sc*8);
  f32x4 ev = {};
  if (tid < 32) ev = *(const f32x4*)(evsrc + m0b);
  unsigned long long aw = bitsT[(size_t)(m0b >> 6)*N + n];

  #pragma unroll 1
  for (int mt = 0; mt < mlen; mt += 64){
    const int m0 = m0b + mt;
    const int buf = (mt >> 6) & 1;
    const unsigned long long adjw = aw;
    // ---- write staged tile (regs from previous iteration) ----
    *(int4*)&Bt[buf][so*64      + slot*8] = sv0;
    *(int4*)&Bt[buf][(so+32)*64 + slot*8] = sv1;
    if (tid < 32) *(f32x4*)&Et[buf][tid << 2] = ev;
    // ---- prefetch next tile ----
    if (mt + 64 < mlen){
      sv0 = *(const int4*)(Wb + (size_t)so*N      + m0 + 64 + sc*8);
      sv1 = *(const int4*)(Wb + (size_t)(so+32)*N + m0 + 64 + sc*8);
      if (tid < 32) ev = *(const f32x4*)(evsrc + m0 + 64);
      aw = bitsT[(size_t)((m0 + 64) >> 6)*N + n];
    }
    __syncthreads();                 // Bt/Et of buf visible
    // ---- A-build: w = max(e2p*e1p, e2n*e1n), masked, cvt_pkrtz pack ----
    const float* Eb = &Et[buf][0];
    half8 Afr[4];
    #pragma unroll
    for (int ks = 0; ks < 4; ++ks){
      const int mo = ks*16 + kg2*8;
      f32x4 pa = *(const f32x4*)&Eb[mo];
      f32x4 pb = *(const f32x4*)&Eb[mo + 4];
      f32x4 qa = *(const f32x4*)&Eb[64 + mo];
      f32x4 qb = *(const f32x4*)&Eb[64 + mo + 4];
      uint32_t bb = (uint32_t)(adjw >> mo) & 0xFFu;
      float tv[8];
      #pragma unroll
      for (int j = 0; j < 4; ++j){
        tv[j]   = fmaxf(pa[j]*rp, qa[j]*rn);
        tv[4+j] = fmaxf(pb[j]*rp, qb[j]*rn);
      }
      union { fp16x2 d[4]; half8 v; } u;
      #pragma unroll
      for (int p = 0; p < 4; ++p){
        float a0 = (bb & (1u << (2*p)))     ? tv[2*p]   : 0.f;
        float a1 = (bb & (1u << (2*p + 1))) ? tv[2*p+1] : 0.f;
        u.d[p] = __builtin_amdgcn_cvt_pkrtz(a0, a1);
      }
      Afr[ks] = u.v;
    }
    // ---- MFMA: 4 k-steps x (2 col-blocks + den) ----
    #pragma unroll
    for (int ks = 0; ks < 4; ++ks){
      const int ci = ks*2 + kg2;
      const int sw = (ci ^ (r32 & 7)) << 3;
      half8 B0 = *(const half8*)&Bt[buf][ r32      *64 + sw];
      half8 B1 = *(const half8*)&Bt[buf][(32 + r32)*64 + sw];
      acc0 = __builtin_amdgcn_mfma_f32_32x32x16_f16(Afr[ks], B0, acc0, 0, 0, 0);
      acc1 = __builtin_amdgcn_mfma_f32_32x32x16_f16(Afr[ks], B1, acc1, 0, 0, 0);
      accD = __builtin_amdgcn_mfma_f32_32x32x16_f16(Afr[ks], BD, accD, 0, 0, 0);
    }
  }

  float* nb = num + ((size_t)(c*Hn + h)*N + n0 + w*32)*64;
  #pragma unroll
  for (int r = 0; r < 16; ++r){
    int row = (r & 3) + 8*(r >> 2) + 4*kg2;
    nb[(size_t)row*64 +      r32] = acc0[r];
    nb[(size_t)row*64 + 32 + r32] = acc1[r];
  }
  if (r32 == 0){
    float* db = den + (size_t)(c*Hn + h)*N + n0 + w*32;
    #pragma unroll
    for (int r = 0; r < 16; ++r){
      int row = (r & 3) + 8*(r >> 2) + 4*kg2;
      db[row] = accD[r];
    }
  }
}

// ---------------- finalize layer 2: out = elu(sum num / sum den) -----------
__global__ __launch_bounds__(256) void fin2_kernel(const float* __restrict__ num,
                                                   const float* __restrict__ den,
                                                   float* __restrict__ out, int nch){
  int idx4 = blockIdx.x * 256 + threadIdx.x;    // over N*64/4 = 65536
  int n = idx4 >> 4;
  const f32x4* num4 = (const f32x4*)num;
  f32x4 s = {};
  float d = 0.f;
  for (int cc = 0; cc < nch; ++cc){
    s += num4[(size_t)cc*(N*16) + idx4];
    d += den[(size_t)cc*N + n];
  }
  float inv = 1.f / d;
  f32x4 r;
  #pragma unroll
  for (int j = 0; j < 4; ++j) r[j] = elu_f(s[j] * inv);
  *(f32x4*)(out + (size_t)idx4*4) = r;
}

extern "C" void kernel_launch(void* const* d_in, const int* in_sizes, int n_in,
                              void* d_out, int out_size, void* d_ws, size_t ws_size,
                              hipStream_t stream){
  const float* x       = (const float*)d_in[0];
  const int*   adj     = (const int*)d_in[1];
  const float* W_heads = (const float*)d_in[3];
  const float* a_heads = (const float*)d_in[4];
  const float* W_out   = (const float*)d_in[5];
  const float* a_out   = (const float*)d_in[6];
  float* out = (float*)d_out;
  char* ws = (char*)d_ws;

  const size_t MB = 1u << 20;
  const size_t KB = 1u << 10;
  unsigned long long* bitsT = (unsigned long long*)(ws);
  ushort* Wh1T = (ushort*)(ws + 2*MB);
  ushort* Wh2T = (ushort*)(ws + 2*MB);
  float* e1p1 = (float*)(ws + 6*MB);
  float* e1n1 = (float*)(ws + 6*MB + 128*KB);
  float* e2p1 = (float*)(ws + 6*MB + 256*KB);
  float* e2n1 = (float*)(ws + 6*MB + 384*KB);
  float* e1p2 = (float*)(ws + 6*MB + 512*KB);
  float* e1n2 = (float*)(ws + 6*MB + 528*KB);
  float* e2p2 = (float*)(ws + 6*MB + 544*KB);
  float* e2n2 = (float*)(ws + 6*MB + 560*KB);
  float* den1 = (float*)(ws + 7*MB);
  float* den2 = (float*)(ws + 8*MB);
  float* num1 = (float*)(ws + 9*MB);
  float* num2 = num1;

  const int nch1 = (ws_size >= (size_t)41*MB) ? 4 : 2;
  const int nch2 = 16;

  mask_kernel<<<1024, 256, 0, stream>>>(adj, bitsT);
  wh1f_kernel<<<256, 256, 0, stream>>>(x, W_heads, a_heads, Wh1T, e1p1, e1n1, e2p1, e2n1);
  attn_kernel<<<32*8*nch1, 256, 0, stream>>>(Wh1T, bitsT, e1p1, e1n1, e2p1, e2n1,
                                             num1, den1, 8, nch1);
  wh2f_kernel<<<256, 256, 0, stream>>>(num1, den1, W_out, a_out, Wh2T,
                                       e1p2, e1n2, e2p2, e2n2, nch1);
  attn_kernel<<<32*1*nch2, 256, 0, stream>>>(Wh2T, bitsT, e1p2, e1n2, e2p2, e2n2,
                                             num2, den2, 1, nch2);
  fin2_kernel<<<256, 256, 0, stream>>>(num2, den2, out, nch2);
}